// Round 4
// baseline (487.247 us; speedup 1.0000x reference)
//
#include <hip/hip_runtime.h>
#include <stdint.h>

typedef unsigned short u16;
typedef __bf16 bf16x8 __attribute__((ext_vector_type(8)));
typedef float f32x4 __attribute__((ext_vector_type(4)));

#define SEQ   2048
#define EMBED 4096
#define KDIM  4096
#define NH    32
#define NKV   16
#define HD    128
#define KVW   2048   // N_KV_HEADS * HD

__device__ __forceinline__ float bf2f(u16 u) {
  union { uint32_t u; float f; } v; v.u = ((uint32_t)u) << 16; return v.f;
}
__device__ __forceinline__ u16 f2bf(float f) {
  union { float f; uint32_t u; } v; v.f = f;
  return (u16)((v.u + 0x7FFFu + ((v.u >> 16) & 1u)) >> 16);
}
__device__ __forceinline__ void g2l16(const u16* g, u16* l) {
  __builtin_amdgcn_global_load_lds(
      (const __attribute__((address_space(1))) uint32_t*)g,
      (__attribute__((address_space(3))) uint32_t*)l, 16, 0, 0);
}

// ---------------- x: f32 -> bf16, same layout ----------------
__global__ __launch_bounds__(256) void convert_x(
    const float* __restrict__ X, u16* __restrict__ Xb, int nquad) {
  for (int i = blockIdx.x * 256 + threadIdx.x; i < nquad;
       i += gridDim.x * 256) {
    float4 v = *(const float4*)(X + (size_t)i * 4);
    ushort4 o;
    o.x = f2bf(v.x); o.y = f2bf(v.y); o.z = f2bf(v.z); o.w = f2bf(v.w);
    *(ushort4*)(Xb + (size_t)i * 4) = o;
  }
}

// ---------------- transpose+convert: Wt[n][k] = bf16(W[k][n]) ----------------
__global__ __launch_bounds__(256) void transpose_cvt(
    const float* __restrict__ W, u16* __restrict__ Wt, int K, int N) {
  __shared__ u16 tile[64][68];
  const int t = threadIdx.x;
  const int n0 = blockIdx.x * 64, k0 = blockIdx.y * 64;
#pragma unroll
  for (int i = 0; i < 4; i++) {
    int c = i * 256 + t;
    int r = c >> 4, cq = c & 15;
    float4 v = *(const float4*)(W + (size_t)(k0 + r) * N + n0 + cq * 4);
    tile[r][cq * 4 + 0] = f2bf(v.x); tile[r][cq * 4 + 1] = f2bf(v.y);
    tile[r][cq * 4 + 2] = f2bf(v.z); tile[r][cq * 4 + 3] = f2bf(v.w);
  }
  __syncthreads();
#pragma unroll
  for (int i = 0; i < 4; i++) {
    int c = i * 256 + t;
    int rn = c >> 4, cq = c & 15;
    ushort4 v;
    v.x = tile[cq * 4 + 0][rn];
    v.y = tile[cq * 4 + 1][rn];
    v.z = tile[cq * 4 + 2][rn];
    v.w = tile[cq * 4 + 3][rn];
    *(ushort4*)(Wt + (size_t)(n0 + rn) * K + k0 + cq * 4) = v;
  }
}

// ================= 8-phase 256x256 GEMM =================
// MODE 1 (QKV): grid 256; N-regions Q(0..4095) K(..6143) Vt(..8191, transposed)
// MODE 0 (out-proj): grid 128; single B, f32 output
template <int MODE>
__global__ __launch_bounds__(512, 2) void gemm8(
    const u16* __restrict__ A,
    const u16* __restrict__ B0, const u16* __restrict__ B1,
    const u16* __restrict__ B2,
    u16* __restrict__ Qo, u16* __restrict__ Ko, u16* __restrict__ Vt,
    float* __restrict__ Cf) {
  __shared__ __align__(16) u16 As[2][256 * 64];
  __shared__ __align__(16) u16 Bs[2][256 * 64];
  const int t = threadIdx.x;
  const int lane = t & 63;
  const int w = t >> 6;          // 0..7
  const int wr = w >> 2;         // 0..1  (M half)
  const int wc = w & 3;          // 0..3  (N quarter)
  const int g = lane >> 4;
  const int l15 = lane & 15;

  // T1: XCD-chunked bijective swizzle
  const int bid = blockIdx.x;
  int mb, nb;
  if (MODE == 1) {
    const int swz = (bid & 7) * 32 + (bid >> 3);
    mb = swz & 7; nb = swz >> 3;          // nb 0..31
  } else {
    const int swz = (bid & 7) * 16 + (bid >> 3);
    mb = swz & 7; nb = swz >> 3;          // nb 0..15
  }
  const int m0 = mb * 256;

  const u16* Bt; int nrow0;
  if (MODE == 1) {
    if (nb < 16)      { Bt = B0; nrow0 = nb * 256; }
    else if (nb < 24) { Bt = B1; nrow0 = (nb - 16) * 256; }
    else              { Bt = B2; nrow0 = (nb - 24) * 256; }
  } else { Bt = B0; nrow0 = nb * 256; }

  auto stageA = [&](int buf, int kt, int h) {
#pragma unroll
    for (int i = 0; i < 2; i++) {
      int c = i * 512 + t;
      int row = c >> 3, sp = c & 7;
      int col = (sp ^ (row & 7)) << 3;
      g2l16(A + (size_t)(m0 + h * 128 + row) * KDIM + kt + col,
            &As[buf][h * 8192 + c * 8]);
    }
  };
  auto stageB = [&](int buf, int kt, int h) {
#pragma unroll
    for (int i = 0; i < 2; i++) {
      int c = i * 512 + t;
      int row = c >> 3, sp = c & 7;
      int col = (sp ^ (row & 7)) << 3;
      g2l16(Bt + (size_t)(nrow0 + h * 128 + row) * KDIM + kt + col,
            &Bs[buf][h * 8192 + c * 8]);
    }
  };

  f32x4 acc[8][4];
#pragma unroll
  for (int i = 0; i < 8; i++)
#pragma unroll
    for (int j = 0; j < 4; j++) acc[i][j] = (f32x4){0.f, 0.f, 0.f, 0.f};

  stageA(0, 0, 0); stageA(0, 0, 1);
  stageB(0, 0, 0); stageB(0, 0, 1);
  stageA(1, 64, 0); stageA(1, 64, 1);
  asm volatile("s_waitcnt vmcnt(4)" ::: "memory");
  __builtin_amdgcn_s_barrier();

  const int NT = KDIM / 64;  // 64
  for (int ti = 0; ti < NT; ++ti) {
    const int cur = ti & 1;
    const u16* Asc = As[cur];
    const u16* Bsc = Bs[cur];
    const int ktn  = (ti + 1) * 64;
    const int ktn2 = (ti + 2) * 64;
    bf16x8 a0[2][4], a1[2][4], b0[2][2], b1[2][2];

    // phase 0: read A(mh0)+B(nh0); stage (t+1).B.h0
#pragma unroll
    for (int kk = 0; kk < 2; kk++)
#pragma unroll
      for (int mi = 0; mi < 4; mi++) {
        int r = wr * 128 + mi * 16 + l15;
        int slot = (kk * 4 + g) ^ (r & 7);
        a0[kk][mi] = *(const bf16x8*)(Asc + r * 64 + slot * 8);
      }
#pragma unroll
    for (int kk = 0; kk < 2; kk++)
#pragma unroll
      for (int ni = 0; ni < 2; ni++) {
        int r = wc * 64 + ni * 16 + l15;
        int slot = (kk * 4 + g) ^ (r & 7);
        b0[kk][ni] = *(const bf16x8*)(Bsc + r * 64 + slot * 8);
      }
    if (ti + 1 < NT) stageB(cur ^ 1, ktn, 0);
    __builtin_amdgcn_s_barrier();
    asm volatile("s_waitcnt lgkmcnt(0)" ::: "memory");
    __builtin_amdgcn_sched_barrier(0);
    __builtin_amdgcn_s_setprio(1);
#pragma unroll
    for (int mi = 0; mi < 4; mi++)
#pragma unroll
      for (int ni = 0; ni < 2; ni++)
#pragma unroll
        for (int kk = 0; kk < 2; kk++)
          acc[mi][ni] = __builtin_amdgcn_mfma_f32_16x16x32_bf16(
              a0[kk][mi], b0[kk][ni], acc[mi][ni], 0, 0, 0);
    __builtin_amdgcn_s_setprio(0);
    __builtin_amdgcn_s_barrier();

    // phase 1: read B(nh1); stage (t+1).B.h1
#pragma unroll
    for (int kk = 0; kk < 2; kk++)
#pragma unroll
      for (int ni = 0; ni < 2; ni++) {
        int r = wc * 64 + (ni + 2) * 16 + l15;
        int slot = (kk * 4 + g) ^ (r & 7);
        b1[kk][ni] = *(const bf16x8*)(Bsc + r * 64 + slot * 8);
      }
    if (ti + 1 < NT) stageB(cur ^ 1, ktn, 1);
    __builtin_amdgcn_s_barrier();
    asm volatile("s_waitcnt lgkmcnt(0)" ::: "memory");
    __builtin_amdgcn_sched_barrier(0);
    __builtin_amdgcn_s_setprio(1);
#pragma unroll
    for (int mi = 0; mi < 4; mi++)
#pragma unroll
      for (int ni = 0; ni < 2; ni++)
#pragma unroll
        for (int kk = 0; kk < 2; kk++)
          acc[mi][ni + 2] = __builtin_amdgcn_mfma_f32_16x16x32_bf16(
              a0[kk][mi], b1[kk][ni], acc[mi][ni + 2], 0, 0, 0);
    __builtin_amdgcn_s_setprio(0);
    __builtin_amdgcn_s_barrier();

    // phase 2: read A(mh1)
#pragma unroll
    for (int kk = 0; kk < 2; kk++)
#pragma unroll
      for (int mi = 0; mi < 4; mi++) {
        int r = wr * 128 + 64 + mi * 16 + l15;
        int slot = (kk * 4 + g) ^ (r & 7);
        a1[kk][mi] = *(const bf16x8*)(Asc + r * 64 + slot * 8);
      }
    __builtin_amdgcn_s_barrier();
    asm volatile("s_waitcnt lgkmcnt(0)" ::: "memory");
    __builtin_amdgcn_sched_barrier(0);
    __builtin_amdgcn_s_setprio(1);
#pragma unroll
    for (int mi = 0; mi < 4; mi++)
#pragma unroll
      for (int ni = 0; ni < 2; ni++)
#pragma unroll
        for (int kk = 0; kk < 2; kk++)
          acc[mi + 4][ni + 2] = __builtin_amdgcn_mfma_f32_16x16x32_bf16(
              a1[kk][mi], b1[kk][ni], acc[mi + 4][ni + 2], 0, 0, 0);
    __builtin_amdgcn_s_setprio(0);
    __builtin_amdgcn_s_barrier();

    // phase 3: stage (t+2).A into buf[cur]
    if (ti + 2 < NT) { stageA(cur, ktn2, 0); stageA(cur, ktn2, 1); }
    __builtin_amdgcn_s_barrier();
    __builtin_amdgcn_s_setprio(1);
#pragma unroll
    for (int mi = 0; mi < 4; mi++)
#pragma unroll
      for (int ni = 0; ni < 2; ni++)
#pragma unroll
        for (int kk = 0; kk < 2; kk++)
          acc[mi + 4][ni] = __builtin_amdgcn_mfma_f32_16x16x32_bf16(
              a1[kk][mi], b0[kk][ni], acc[mi + 4][ni], 0, 0, 0);
    __builtin_amdgcn_s_setprio(0);
    if (ti + 2 < NT)      asm volatile("s_waitcnt vmcnt(4)" ::: "memory");
    else if (ti + 1 < NT) asm volatile("s_waitcnt vmcnt(0)" ::: "memory");
    __builtin_amdgcn_s_barrier();
  }

#pragma unroll
  for (int mi = 0; mi < 8; mi++) {
#pragma unroll
    for (int ni = 0; ni < 4; ni++) {
      int rowg = m0 + wr * 128 + mi * 16 + g * 4;
      int ncol = nb * 256 + wc * 64 + ni * 16 + l15;
      if (MODE == 0) {
#pragma unroll
        for (int r = 0; r < 4; r++)
          Cf[(size_t)(rowg + r) * 4096 + ncol] = acc[mi][ni][r];
      } else if (nb < 16) {
#pragma unroll
        for (int r = 0; r < 4; r++)
          Qo[(size_t)(rowg + r) * EMBED + ncol] = f2bf(acc[mi][ni][r]);
      } else if (nb < 24) {
        int nc = ncol - 4096;
#pragma unroll
        for (int r = 0; r < 4; r++)
          Ko[(size_t)(rowg + r) * KVW + nc] = f2bf(acc[mi][ni][r]);
      } else {
        int nc = ncol - 6144;  // kv_head*128 + d
        ushort4 v;
        v.x = f2bf(acc[mi][ni][0]); v.y = f2bf(acc[mi][ni][1]);
        v.z = f2bf(acc[mi][ni][2]); v.w = f2bf(acc[mi][ni][3]);
        *(ushort4*)(Vt + (size_t)nc * SEQ + rowg) = v;
      }
    }
  }
}

// ---------------- RoPE (in place) on Q [2048][4096] and K [2048][2048] ----
__global__ __launch_bounds__(256) void rope_kernel(
    u16* __restrict__ Q, u16* __restrict__ Kb,
    const float* __restrict__ freqs, const int* __restrict__ start_pos) {
  const int sp = start_pos[0];
  const float qscale = 0.08838834764831845f;  // 1/sqrt(128)
  const int total_q = SEQ * EMBED / 2;
  const int total_k = SEQ * KVW / 2;
  const int total = total_q + total_k;
  for (int idx = blockIdx.x * 256 + threadIdx.x; idx < total;
       idx += gridDim.x * 256) {
    u16* buf; int row, pi; bool isq = idx < total_q;
    if (isq) { row = idx >> 11; pi = idx & 2047; buf = Q + (size_t)row * EMBED; }
    else { int j = idx - total_q; row = j >> 10; pi = j & 1023; buf = Kb + (size_t)row * KVW; }
    int i = pi & 63;
    float2 cs = *(const float2*)(freqs + (size_t)(sp + row) * 128 + i * 2);
    float c = cs.x, s = cs.y;
    ushort2 tv = *(ushort2*)(buf + pi * 2);
    float t0 = bf2f(tv.x), t1 = bf2f(tv.y);
    float o0 = t0 * c - t1 * s;
    float o1 = t0 * s + t1 * c;
    if (isq) { o0 *= qscale; o1 *= qscale; }
    ushort2 o; o.x = f2bf(o0); o.y = f2bf(o1);
    *(ushort2*)(buf + pi * 2) = o;
  }
}

// ---------------- flash attention, causal, GQA, double-buffered K/V --------
// Q [2048][4096] (rope'd, pre-scaled), Kb [2048][2048] (rope'd),
// Vt [2048][2048] = [kv*128+d][seq], O [2048][4096]
__global__ __launch_bounds__(256) void attn_kernel(
    const u16* __restrict__ Q, const u16* __restrict__ Kb,
    const u16* __restrict__ Vt, u16* __restrict__ O) {
  // each buffer: K tile (64x128 -> 8192 elems) then V tile (128x64 -> 8192)
  __shared__ __align__(16) u16 KV[2][16384];
  __shared__ u16 Ps[4][16 * 72];

  const int t = threadIdx.x;
  const int lane = t & 63;
  const int w = t >> 6;
  const int g = lane >> 4;
  const int l15 = lane & 15;
  const int qb = blockIdx.x;
  const int h = blockIdx.y;
  const int hk = h >> 1;

  auto stageK = [&](int buf, int kv) {
#pragma unroll
    for (int i = 0; i < 4; i++) {
      int c = i * 256 + t;
      int row = c >> 4, spp = c & 15;
      int col = ((spp ^ (row & 7)) << 3);
      g2l16(Kb + (size_t)(kv * 64 + row) * KVW + hk * HD + col,
            &KV[buf][c * 8]);
    }
  };
  auto stageV = [&](int buf, int kv) {
#pragma unroll
    for (int i = 0; i < 4; i++) {
      int c = i * 256 + t;
      int row = c >> 3, spp = c & 7;
      int col = ((spp ^ (row & 7)) << 3);
      g2l16(Vt + (size_t)(hk * HD + row) * SEQ + kv * 64 + col,
            &KV[buf][8192 + c * 8]);
    }
  };

  // stage Q into KV[1]'s K slot (4 loads), then kv=0 K+V (8 loads)
#pragma unroll
  for (int i = 0; i < 4; i++) {
    int c = i * 256 + t;
    int row = c >> 4, spp = c & 15;
    int col = ((spp ^ (row & 7)) << 3);
    g2l16(Q + (size_t)(qb * 64 + row) * EMBED + h * HD + col,
          &KV[1][c * 8]);
  }
  stageK(0, 0); stageV(0, 0);
  asm volatile("s_waitcnt vmcnt(8)" ::: "memory");   // Q's 4 done
  __builtin_amdgcn_s_barrier();

  bf16x8 qf[4];
  {
    int r = w * 16 + l15;
#pragma unroll
    for (int kk = 0; kk < 4; kk++) {
      int ps = (kk * 4 + g) ^ (r & 7);
      qf[kk] = *(const bf16x8*)(&KV[1][r * 128 + ps * 8]);
    }
  }
  asm volatile("s_waitcnt lgkmcnt(0)" ::: "memory");
  __builtin_amdgcn_s_barrier();   // all qf reads done before buf1 overwritten

  f32x4 oacc[8];
#pragma unroll
  for (int i = 0; i < 8; i++) oacc[i] = (f32x4){0.f, 0.f, 0.f, 0.f};
  float mrow[4] = {-1e30f, -1e30f, -1e30f, -1e30f};
  float lrow[4] = {0.f, 0.f, 0.f, 0.f};

  for (int kv = 0; kv <= qb; kv++) {
    const int cur = kv & 1;
    const u16* Kc = &KV[cur][0];
    const u16* Vc = &KV[cur][8192];
    if (kv < qb) {                       // prefetch next tile
      stageK(cur ^ 1, kv + 1);
      stageV(cur ^ 1, kv + 1);
      asm volatile("s_waitcnt vmcnt(8)" ::: "memory");  // cur's 8 done
    } else {
      asm volatile("s_waitcnt vmcnt(0)" ::: "memory");
    }
    __builtin_amdgcn_s_barrier();

    // S = Q K^T
    f32x4 sfrag[4];
    __builtin_amdgcn_s_setprio(1);
#pragma unroll
    for (int ni = 0; ni < 4; ni++) {
      f32x4 s = (f32x4){0.f, 0.f, 0.f, 0.f};
      int r = ni * 16 + l15;
#pragma unroll
      for (int kk = 0; kk < 4; kk++) {
        int ps = (kk * 4 + g) ^ (r & 7);
        bf16x8 b = *(const bf16x8*)(Kc + r * 128 + ps * 8);
        s = __builtin_amdgcn_mfma_f32_16x16x32_bf16(qf[kk], b, s, 0, 0, 0);
      }
      sfrag[ni] = s;
    }
    __builtin_amdgcn_s_setprio(0);
    if (kv == qb) {
#pragma unroll
      for (int ni = 0; ni < 4; ni++) {
        int colg = kv * 64 + ni * 16 + l15;
#pragma unroll
        for (int r = 0; r < 4; r++) {
          int qg = qb * 64 + w * 16 + g * 4 + r;
          if (colg > qg) sfrag[ni][r] = -1e30f;
        }
      }
    }
    float pm[4];
#pragma unroll
    for (int r = 0; r < 4; r++) {
      float m = fmaxf(fmaxf(sfrag[0][r], sfrag[1][r]),
                      fmaxf(sfrag[2][r], sfrag[3][r]));
      m = fmaxf(m, __shfl_xor(m, 1));
      m = fmaxf(m, __shfl_xor(m, 2));
      m = fmaxf(m, __shfl_xor(m, 4));
      m = fmaxf(m, __shfl_xor(m, 8));
      pm[r] = m;
    }
    float sc[4], rs[4];
#pragma unroll
    for (int r = 0; r < 4; r++) {
      float mnew = fmaxf(mrow[r], pm[r]);
      sc[r] = __expf(mrow[r] - mnew);
      mrow[r] = mnew;
      rs[r] = 0.f;
    }
#pragma unroll
    for (int ni = 0; ni < 4; ni++) {
#pragma unroll
      for (int r = 0; r < 4; r++) {
        float p = __expf(sfrag[ni][r] - mrow[r]);
        rs[r] += p;
        Ps[w][(g * 4 + r) * 72 + ni * 16 + l15] = f2bf(p);
      }
    }
#pragma unroll
    for (int r = 0; r < 4; r++) {
      float x = rs[r];
      x += __shfl_xor(x, 1);
      x += __shfl_xor(x, 2);
      x += __shfl_xor(x, 4);
      x += __shfl_xor(x, 8);
      lrow[r] = lrow[r] * sc[r] + x;
    }
#pragma unroll
    for (int nf = 0; nf < 8; nf++)
#pragma unroll
      for (int r = 0; r < 4; r++) oacc[nf][r] *= sc[r];

    asm volatile("s_waitcnt lgkmcnt(0)" ::: "memory");

    bf16x8 pa[2];
#pragma unroll
    for (int kk = 0; kk < 2; kk++)
      pa[kk] = *(const bf16x8*)(&Ps[w][l15 * 72 + kk * 32 + g * 8]);
    __builtin_amdgcn_s_setprio(1);
#pragma unroll
    for (int nf = 0; nf < 8; nf++) {
      int r = nf * 16 + l15;
#pragma unroll
      for (int kk = 0; kk < 2; kk++) {
        int ps = (kk * 4 + g) ^ (r & 7);
        bf16x8 b = *(const bf16x8*)(Vc + r * 64 + ps * 8);
        oacc[nf] = __builtin_amdgcn_mfma_f32_16x16x32_bf16(pa[kk], b, oacc[nf], 0, 0, 0);
      }
    }
    __builtin_amdgcn_s_setprio(0);
    __builtin_amdgcn_s_barrier();   // done reading cur before it's overwritten
  }

#pragma unroll
  for (int nf = 0; nf < 8; nf++) {
#pragma unroll
    for (int r = 0; r < 4; r++) {
      int rowg = qb * 64 + w * 16 + g * 4 + r;
      float v = oacc[nf][r] / lrow[r];
      O[(size_t)rowg * EMBED + h * HD + nf * 16 + l15] = f2bf(v);
    }
  }
}

extern "C" void kernel_launch(void* const* d_in, const int* in_sizes, int n_in,
                              void* d_out, int out_size, void* d_ws, size_t ws_size,
                              hipStream_t stream) {
  const float* x  = (const float*)d_in[0];
  const float* fc = (const float*)d_in[1];
  const float* wq = (const float*)d_in[2];
  const float* wk = (const float*)d_in[3];
  const float* wv = (const float*)d_in[4];
  const float* wo = (const float*)d_in[5];
  const int* sp = (const int*)d_in[6];

  char* ws = (char*)d_ws;
  u16* wqT = (u16*)(ws);                      // bf16 [4096][4096]
  u16* wkT = (u16*)(ws + 33554432ull);        // bf16 [2048][4096]
  u16* wvT = (u16*)(ws + 50331648ull);        // bf16 [2048][4096]
  u16* woT = (u16*)(ws + 67108864ull);        // bf16 [4096][4096]
  u16* xb  = (u16*)(ws + 100663296ull);       // bf16 [2048][4096]
  u16* Qb  = (u16*)(ws + 117440512ull);       // bf16 [2048][4096]
  u16* Kb  = (u16*)(ws + 134217728ull);       // bf16 [2048][2048]
  u16* Vt  = (u16*)(ws + 142606336ull);       // bf16 [2048][2048]
  u16* Ob  = (u16*)(ws + 150994944ull);       // bf16 [2048][4096]

  convert_x<<<dim3(2048), 256, 0, stream>>>(x, xb, SEQ * EMBED / 4);
  transpose_cvt<<<dim3(64, 64), 256, 0, stream>>>(wq, wqT, 4096, 4096);
  transpose_cvt<<<dim3(32, 64), 256, 0, stream>>>(wk, wkT, 4096, 2048);
  transpose_cvt<<<dim3(32, 64), 256, 0, stream>>>(wv, wvT, 4096, 2048);
  transpose_cvt<<<dim3(64, 64), 256, 0, stream>>>(wo, woT, 4096, 4096);

  gemm8<1><<<dim3(256), 512, 0, stream>>>(xb, wqT, wkT, wvT,
                                          Qb, Kb, Vt, nullptr);
  rope_kernel<<<dim3(2048), 256, 0, stream>>>(Qb, Kb, fc, sp);
  attn_kernel<<<dim3(32, 32), 256, 0, stream>>>(Qb, Kb, Vt, Ob);
  gemm8<0><<<dim3(128), 512, 0, stream>>>(Ob, woT, nullptr, nullptr,
                                          nullptr, nullptr, nullptr,
                                          (float*)d_out);
}

// Round 5
// 361.437 us; speedup vs baseline: 1.3481x; 1.3481x over previous
//
#include <hip/hip_runtime.h>
#include <stdint.h>

typedef unsigned short u16;
typedef __bf16 bf16x8 __attribute__((ext_vector_type(8)));
typedef float f32x4 __attribute__((ext_vector_type(4)));

#define SEQ   2048
#define EMBED 4096
#define KDIM  4096
#define NH    32
#define NKV   16
#define HD    128
#define KVW   2048   // N_KV_HEADS * HD

__device__ __forceinline__ float bf2f(u16 u) {
  union { uint32_t u; float f; } v; v.u = ((uint32_t)u) << 16; return v.f;
}
__device__ __forceinline__ u16 f2bf(float f) {
  union { float f; uint32_t u; } v; v.f = f;
  return (u16)((v.u + 0x7FFFu + ((v.u >> 16) & 1u)) >> 16);
}
__device__ __forceinline__ void g2l16(const u16* g, u16* l) {
  __builtin_amdgcn_global_load_lds(
      (const __attribute__((address_space(1))) uint32_t*)g,
      (__attribute__((address_space(3))) uint32_t*)l, 16, 0, 0);
}

// ---------------- x: f32 -> bf16, same layout ----------------
__global__ __launch_bounds__(256) void convert_x(
    const float* __restrict__ X, u16* __restrict__ Xb, int nquad) {
  for (int i = blockIdx.x * 256 + threadIdx.x; i < nquad;
       i += gridDim.x * 256) {
    float4 v = *(const float4*)(X + (size_t)i * 4);
    ushort4 o;
    o.x = f2bf(v.x); o.y = f2bf(v.y); o.z = f2bf(v.z); o.w = f2bf(v.w);
    *(ushort4*)(Xb + (size_t)i * 4) = o;
  }
}

// ---------------- transpose+convert: Wt[n][k] = bf16(W[k][n]) ----------------
__global__ __launch_bounds__(256) void transpose_cvt(
    const float* __restrict__ W, u16* __restrict__ Wt, int K, int N) {
  __shared__ u16 tile[64][68];
  const int t = threadIdx.x;
  const int n0 = blockIdx.x * 64, k0 = blockIdx.y * 64;
#pragma unroll
  for (int i = 0; i < 4; i++) {
    int c = i * 256 + t;
    int r = c >> 4, cq = c & 15;
    float4 v = *(const float4*)(W + (size_t)(k0 + r) * N + n0 + cq * 4);
    tile[r][cq * 4 + 0] = f2bf(v.x); tile[r][cq * 4 + 1] = f2bf(v.y);
    tile[r][cq * 4 + 2] = f2bf(v.z); tile[r][cq * 4 + 3] = f2bf(v.w);
  }
  __syncthreads();
#pragma unroll
  for (int i = 0; i < 4; i++) {
    int c = i * 256 + t;
    int rn = c >> 4, cq = c & 15;
    ushort4 v;
    v.x = tile[cq * 4 + 0][rn];
    v.y = tile[cq * 4 + 1][rn];
    v.z = tile[cq * 4 + 2][rn];
    v.w = tile[cq * 4 + 3][rn];
    *(ushort4*)(Wt + (size_t)(n0 + rn) * K + k0 + cq * 4) = v;
  }
}

// ================= 8-phase 256x256 GEMM for QKV =================
__global__ __launch_bounds__(512, 2) void gemm8_qkv(
    const u16* __restrict__ A,
    const u16* __restrict__ B0, const u16* __restrict__ B1,
    const u16* __restrict__ B2,
    u16* __restrict__ Qo, u16* __restrict__ Ko, u16* __restrict__ Vt) {
  __shared__ __align__(16) u16 As[2][256 * 64];
  __shared__ __align__(16) u16 Bs[2][256 * 64];
  const int t = threadIdx.x;
  const int lane = t & 63;
  const int w = t >> 6;
  const int wr = w >> 2;
  const int wc = w & 3;
  const int g = lane >> 4;
  const int l15 = lane & 15;

  const int bid = blockIdx.x;
  const int swz = (bid & 7) * 32 + (bid >> 3);
  const int mb = swz & 7;
  const int nb = swz >> 3;
  const int m0 = mb * 256;

  const u16* Bt; int nrow0;
  if (nb < 16)      { Bt = B0; nrow0 = nb * 256; }
  else if (nb < 24) { Bt = B1; nrow0 = (nb - 16) * 256; }
  else              { Bt = B2; nrow0 = (nb - 24) * 256; }

  auto stageA = [&](int buf, int kt, int h) {
#pragma unroll
    for (int i = 0; i < 2; i++) {
      int c = i * 512 + t;
      int row = c >> 3, sp = c & 7;
      int col = (sp ^ (row & 7)) << 3;
      g2l16(A + (size_t)(m0 + h * 128 + row) * KDIM + kt + col,
            &As[buf][h * 8192 + c * 8]);
    }
  };
  auto stageB = [&](int buf, int kt, int h) {
#pragma unroll
    for (int i = 0; i < 2; i++) {
      int c = i * 512 + t;
      int row = c >> 3, sp = c & 7;
      int col = (sp ^ (row & 7)) << 3;
      g2l16(Bt + (size_t)(nrow0 + h * 128 + row) * KDIM + kt + col,
            &Bs[buf][h * 8192 + c * 8]);
    }
  };

  f32x4 acc[8][4];
#pragma unroll
  for (int i = 0; i < 8; i++)
#pragma unroll
    for (int j = 0; j < 4; j++) acc[i][j] = (f32x4){0.f, 0.f, 0.f, 0.f};

  stageA(0, 0, 0); stageA(0, 0, 1);
  stageB(0, 0, 0); stageB(0, 0, 1);
  stageA(1, 64, 0); stageA(1, 64, 1);
  asm volatile("s_waitcnt vmcnt(4)" ::: "memory");
  __builtin_amdgcn_s_barrier();

  const int NT = KDIM / 64;
  for (int ti = 0; ti < NT; ++ti) {
    const int cur = ti & 1;
    const u16* Asc = As[cur];
    const u16* Bsc = Bs[cur];
    const int ktn  = (ti + 1) * 64;
    const int ktn2 = (ti + 2) * 64;
    bf16x8 a0[2][4], a1[2][4], b0[2][2], b1[2][2];

#pragma unroll
    for (int kk = 0; kk < 2; kk++)
#pragma unroll
      for (int mi = 0; mi < 4; mi++) {
        int r = wr * 128 + mi * 16 + l15;
        int slot = (kk * 4 + g) ^ (r & 7);
        a0[kk][mi] = *(const bf16x8*)(Asc + r * 64 + slot * 8);
      }
#pragma unroll
    for (int kk = 0; kk < 2; kk++)
#pragma unroll
      for (int ni = 0; ni < 2; ni++) {
        int r = wc * 64 + ni * 16 + l15;
        int slot = (kk * 4 + g) ^ (r & 7);
        b0[kk][ni] = *(const bf16x8*)(Bsc + r * 64 + slot * 8);
      }
    if (ti + 1 < NT) stageB(cur ^ 1, ktn, 0);
    __builtin_amdgcn_s_barrier();
    asm volatile("s_waitcnt lgkmcnt(0)" ::: "memory");
    __builtin_amdgcn_sched_barrier(0);
    __builtin_amdgcn_s_setprio(1);
#pragma unroll
    for (int mi = 0; mi < 4; mi++)
#pragma unroll
      for (int ni = 0; ni < 2; ni++)
#pragma unroll
        for (int kk = 0; kk < 2; kk++)
          acc[mi][ni] = __builtin_amdgcn_mfma_f32_16x16x32_bf16(
              a0[kk][mi], b0[kk][ni], acc[mi][ni], 0, 0, 0);
    __builtin_amdgcn_s_setprio(0);
    __builtin_amdgcn_s_barrier();

#pragma unroll
    for (int kk = 0; kk < 2; kk++)
#pragma unroll
      for (int ni = 0; ni < 2; ni++) {
        int r = wc * 64 + (ni + 2) * 16 + l15;
        int slot = (kk * 4 + g) ^ (r & 7);
        b1[kk][ni] = *(const bf16x8*)(Bsc + r * 64 + slot * 8);
      }
    if (ti + 1 < NT) stageB(cur ^ 1, ktn, 1);
    __builtin_amdgcn_s_barrier();
    asm volatile("s_waitcnt lgkmcnt(0)" ::: "memory");
    __builtin_amdgcn_sched_barrier(0);
    __builtin_amdgcn_s_setprio(1);
#pragma unroll
    for (int mi = 0; mi < 4; mi++)
#pragma unroll
      for (int ni = 0; ni < 2; ni++)
#pragma unroll
        for (int kk = 0; kk < 2; kk++)
          acc[mi][ni + 2] = __builtin_amdgcn_mfma_f32_16x16x32_bf16(
              a0[kk][mi], b1[kk][ni], acc[mi][ni + 2], 0, 0, 0);
    __builtin_amdgcn_s_setprio(0);
    __builtin_amdgcn_s_barrier();

#pragma unroll
    for (int kk = 0; kk < 2; kk++)
#pragma unroll
      for (int mi = 0; mi < 4; mi++) {
        int r = wr * 128 + 64 + mi * 16 + l15;
        int slot = (kk * 4 + g) ^ (r & 7);
        a1[kk][mi] = *(const bf16x8*)(Asc + r * 64 + slot * 8);
      }
    __builtin_amdgcn_s_barrier();
    asm volatile("s_waitcnt lgkmcnt(0)" ::: "memory");
    __builtin_amdgcn_sched_barrier(0);
    __builtin_amdgcn_s_setprio(1);
#pragma unroll
    for (int mi = 0; mi < 4; mi++)
#pragma unroll
      for (int ni = 0; ni < 2; ni++)
#pragma unroll
        for (int kk = 0; kk < 2; kk++)
          acc[mi + 4][ni + 2] = __builtin_amdgcn_mfma_f32_16x16x32_bf16(
              a1[kk][mi], b1[kk][ni], acc[mi + 4][ni + 2], 0, 0, 0);
    __builtin_amdgcn_s_setprio(0);
    __builtin_amdgcn_s_barrier();

    if (ti + 2 < NT) { stageA(cur, ktn2, 0); stageA(cur, ktn2, 1); }
    __builtin_amdgcn_s_barrier();
    __builtin_amdgcn_s_setprio(1);
#pragma unroll
    for (int mi = 0; mi < 4; mi++)
#pragma unroll
      for (int ni = 0; ni < 2; ni++)
#pragma unroll
        for (int kk = 0; kk < 2; kk++)
          acc[mi + 4][ni] = __builtin_amdgcn_mfma_f32_16x16x32_bf16(
              a1[kk][mi], b0[kk][ni], acc[mi + 4][ni], 0, 0, 0);
    __builtin_amdgcn_s_setprio(0);
    if (ti + 2 < NT)      asm volatile("s_waitcnt vmcnt(4)" ::: "memory");
    else if (ti + 1 < NT) asm volatile("s_waitcnt vmcnt(0)" ::: "memory");
    __builtin_amdgcn_s_barrier();
  }

#pragma unroll
  for (int mi = 0; mi < 8; mi++) {
#pragma unroll
    for (int ni = 0; ni < 4; ni++) {
      int rowg = m0 + wr * 128 + mi * 16 + g * 4;
      int ncol = nb * 256 + wc * 64 + ni * 16 + l15;
      if (nb < 16) {
#pragma unroll
        for (int r = 0; r < 4; r++)
          Qo[(size_t)(rowg + r) * EMBED + ncol] = f2bf(acc[mi][ni][r]);
      } else if (nb < 24) {
        int nc = ncol - 4096;
#pragma unroll
        for (int r = 0; r < 4; r++)
          Ko[(size_t)(rowg + r) * KVW + nc] = f2bf(acc[mi][ni][r]);
      } else {
        int nc = ncol - 6144;  // kv_head*128 + d
        ushort4 v;
        v.x = f2bf(acc[mi][ni][0]); v.y = f2bf(acc[mi][ni][1]);
        v.z = f2bf(acc[mi][ni][2]); v.w = f2bf(acc[mi][ni][3]);
        *(ushort4*)(Vt + (size_t)nc * SEQ + rowg) = v;
      }
    }
  }
}

// ---------------- 128x128 GEMM (out-proj): Cf = A * Bt^T, f32 out ----------
__global__ __launch_bounds__(256) void gemm_bt_f32(
    const u16* __restrict__ A, const u16* __restrict__ Bt,
    float* __restrict__ Cf) {
  __shared__ u16 As[128 * 64];
  __shared__ u16 Bs[128 * 64];
  const int t = threadIdx.x;
  const int lane = t & 63;
  const int w = t >> 6;
  const int wr = w >> 1, wc = w & 1;
  const int g = lane >> 4;
  const int l15 = lane & 15;

  const int flat = blockIdx.x + (int)gridDim.x * blockIdx.y;
  const int swz = (flat & 7) * 64 + (flat >> 3);
  const int m0 = (swz & 15) * 128;
  const int nb = swz >> 4;
  const int nrow0 = nb * 128;

  f32x4 acc[4][4];
#pragma unroll
  for (int i = 0; i < 4; i++)
#pragma unroll
    for (int j = 0; j < 4; j++) acc[i][j] = (f32x4){0.f, 0.f, 0.f, 0.f};

  for (int kt = 0; kt < KDIM; kt += 64) {
#pragma unroll
    for (int i = 0; i < 4; i++) {
      int c = i * 256 + t;
      int row = c >> 3, sp = c & 7;
      int col = ((sp ^ (row & 7)) << 3);
      g2l16(A  + (size_t)(m0 + row)    * KDIM + kt + col, As + c * 8);
      g2l16(Bt + (size_t)(nrow0 + row) * KDIM + kt + col, Bs + c * 8);
    }
    __syncthreads();
#pragma unroll
    for (int kk = 0; kk < 2; kk++) {
      bf16x8 af[4], bfr[4];
#pragma unroll
      for (int mi = 0; mi < 4; mi++) {
        int r = wr * 64 + mi * 16 + l15;
        int ps = (kk * 4 + g) ^ (r & 7);
        af[mi] = *(const bf16x8*)(As + r * 64 + ps * 8);
      }
#pragma unroll
      for (int ni = 0; ni < 4; ni++) {
        int r = wc * 64 + ni * 16 + l15;
        int ps = (kk * 4 + g) ^ (r & 7);
        bfr[ni] = *(const bf16x8*)(Bs + r * 64 + ps * 8);
      }
#pragma unroll
      for (int mi = 0; mi < 4; mi++)
#pragma unroll
        for (int ni = 0; ni < 4; ni++)
          acc[mi][ni] = __builtin_amdgcn_mfma_f32_16x16x32_bf16(
              af[mi], bfr[ni], acc[mi][ni], 0, 0, 0);
    }
    __syncthreads();
  }

#pragma unroll
  for (int mi = 0; mi < 4; mi++)
#pragma unroll
    for (int ni = 0; ni < 4; ni++) {
      int rowg = m0 + wr * 64 + mi * 16 + g * 4;
      int ncol = nb * 128 + wc * 64 + ni * 16 + l15;
#pragma unroll
      for (int r = 0; r < 4; r++)
        Cf[(size_t)(rowg + r) * 4096 + ncol] = acc[mi][ni][r];
    }
}

// ---------------- RoPE (in place) on Q [2048][4096] and K [2048][2048] ----
__global__ __launch_bounds__(256) void rope_kernel(
    u16* __restrict__ Q, u16* __restrict__ Kb,
    const float* __restrict__ freqs, const int* __restrict__ start_pos) {
  const int sp = start_pos[0];
  const float qscale = 0.08838834764831845f;  // 1/sqrt(128)
  const int total_q = SEQ * EMBED / 2;
  const int total_k = SEQ * KVW / 2;
  const int total = total_q + total_k;
  for (int idx = blockIdx.x * 256 + threadIdx.x; idx < total;
       idx += gridDim.x * 256) {
    u16* buf; int row, pi; bool isq = idx < total_q;
    if (isq) { row = idx >> 11; pi = idx & 2047; buf = Q + (size_t)row * EMBED; }
    else { int j = idx - total_q; row = j >> 10; pi = j & 1023; buf = Kb + (size_t)row * KVW; }
    int i = pi & 63;
    float2 cs = *(const float2*)(freqs + (size_t)(sp + row) * 128 + i * 2);
    float c = cs.x, s = cs.y;
    ushort2 tv = *(ushort2*)(buf + pi * 2);
    float t0 = bf2f(tv.x), t1 = bf2f(tv.y);
    float o0 = t0 * c - t1 * s;
    float o1 = t0 * s + t1 * c;
    if (isq) { o0 *= qscale; o1 *= qscale; }
    ushort2 o; o.x = f2bf(o0); o.y = f2bf(o1);
    *(ushort2*)(buf + pi * 2) = o;
  }
}

// ---------------- flash attention, causal, GQA ----------------
// Swapped QK^T (mfma(K,Q)) -> lane owns one q-row: softmax is 2 shfl deep.
// Q [2048][4096] (rope'd, pre-scaled), Kb [2048][2048], Vt [2048][2048],
// O [2048][4096]. Grid: 1024 1-D, qb descending (longest blocks first).
__global__ __launch_bounds__(256, 4) void attn_kernel(
    const u16* __restrict__ Q, const u16* __restrict__ Kb,
    const u16* __restrict__ Vt, u16* __restrict__ O) {
  __shared__ __align__(16) u16 KV[16384];   // K: [0,8192) 64x128, V: [8192,..) 128x64
  __shared__ u16 Ps[4][16 * 72];

  const int t = threadIdx.x;
  const int lane = t & 63;
  const int w = t >> 6;
  const int g = lane >> 4;
  const int l15 = lane & 15;
  const int bid = blockIdx.x;
  const int qb = 31 - (bid >> 5);
  const int h = bid & 31;
  const int hk = h >> 1;

  auto stageK = [&](int kv) {
#pragma unroll
    for (int i = 0; i < 4; i++) {
      int c = i * 256 + t;
      int row = c >> 4, spp = c & 15;
      int col = ((spp ^ (row & 7)) << 3);
      g2l16(Kb + (size_t)(kv * 64 + row) * KVW + hk * HD + col, &KV[c * 8]);
    }
  };
  auto stageV = [&](int kv) {
#pragma unroll
    for (int i = 0; i < 4; i++) {
      int c = i * 256 + t;
      int row = c >> 3, spp = c & 7;
      int col = ((spp ^ (row & 7)) << 3);
      g2l16(Vt + (size_t)(hk * HD + row) * SEQ + kv * 64 + col,
            &KV[8192 + c * 8]);
    }
  };

  // stage Q (64x128) into the K slot, read fragments, then release
#pragma unroll
  for (int i = 0; i < 4; i++) {
    int c = i * 256 + t;
    int row = c >> 4, spp = c & 15;
    int col = ((spp ^ (row & 7)) << 3);
    g2l16(Q + (size_t)(qb * 64 + row) * EMBED + h * HD + col, &KV[c * 8]);
  }
  asm volatile("s_waitcnt vmcnt(0)" ::: "memory");
  __builtin_amdgcn_s_barrier();

  bf16x8 qf[4];
  {
    int r = w * 16 + l15;
#pragma unroll
    for (int kk = 0; kk < 4; kk++) {
      int ps = (kk * 4 + g) ^ (r & 7);
      qf[kk] = *(const bf16x8*)(&KV[r * 128 + ps * 8]);
    }
  }
  asm volatile("s_waitcnt lgkmcnt(0)" ::: "memory");
  __builtin_amdgcn_s_barrier();   // all qf reads done before K overwrites

  f32x4 oacc[8];
#pragma unroll
  for (int i = 0; i < 8; i++) oacc[i] = (f32x4){0.f, 0.f, 0.f, 0.f};
  float mrow = -1e30f, lrow = 0.f;
  const int qg = qb * 64 + w * 16 + l15;   // this lane's q-row

  for (int kv = 0; kv <= qb; kv++) {
    stageK(kv); stageV(kv);
    asm volatile("s_waitcnt vmcnt(0)" ::: "memory");
    __builtin_amdgcn_s_barrier();

    // S^T = K Q^T : lane holds S[k = kv*64+ni*16+g*4+r][q = qg]
    f32x4 sfragT[4];
    __builtin_amdgcn_s_setprio(1);
#pragma unroll
    for (int ni = 0; ni < 4; ni++) {
      f32x4 s = (f32x4){0.f, 0.f, 0.f, 0.f};
      int r = ni * 16 + l15;
#pragma unroll
      for (int kk = 0; kk < 4; kk++) {
        int ps = (kk * 4 + g) ^ (r & 7);
        bf16x8 a = *(const bf16x8*)(&KV[r * 128 + ps * 8]);
        s = __builtin_amdgcn_mfma_f32_16x16x32_bf16(a, qf[kk], s, 0, 0, 0);
      }
      sfragT[ni] = s;
    }
    __builtin_amdgcn_s_setprio(0);

    if (kv == qb) {  // diagonal block: causal mask
#pragma unroll
      for (int ni = 0; ni < 4; ni++) {
        int colg = kv * 64 + ni * 16 + g * 4;
#pragma unroll
        for (int r = 0; r < 4; r++)
          if (colg + r > qg) sfragT[ni][r] = -1e30f;
      }
    }

    // row stats: 15 in-register max + 2 shfl (row spread over 4 g-lanes)
    float m16 = sfragT[0][0];
#pragma unroll
    for (int ni = 0; ni < 4; ni++)
#pragma unroll
      for (int r = 0; r < 4; r++) m16 = fmaxf(m16, sfragT[ni][r]);
    m16 = fmaxf(m16, __shfl_xor(m16, 16));
    m16 = fmaxf(m16, __shfl_xor(m16, 32));
    float mnew = fmaxf(mrow, m16);
    float sc = __expf(mrow - mnew);
    mrow = mnew;

    float rsum = 0.f;
#pragma unroll
    for (int ni = 0; ni < 4; ni++) {
#pragma unroll
      for (int r = 0; r < 4; r++) {
        float p = __expf(sfragT[ni][r] - mrow);
        rsum += p;
        Ps[w][l15 * 72 + ni * 16 + g * 4 + r] = f2bf(p);
      }
    }
    rsum += __shfl_xor(rsum, 16);
    rsum += __shfl_xor(rsum, 32);
    lrow = lrow * sc + rsum;

    // broadcast sc from q=l15 space to accumulator q=g*4+r space
    float scr[4];
#pragma unroll
    for (int r = 0; r < 4; r++) scr[r] = __shfl(sc, g * 4 + r, 64);
#pragma unroll
    for (int nf = 0; nf < 8; nf++)
#pragma unroll
      for (int r = 0; r < 4; r++) oacc[nf][r] *= scr[r];

    asm volatile("s_waitcnt lgkmcnt(0)" ::: "memory");

    // O += P V  (pa layout [q][k] unchanged)
    bf16x8 pa[2];
#pragma unroll
    for (int kk = 0; kk < 2; kk++)
      pa[kk] = *(const bf16x8*)(&Ps[w][l15 * 72 + kk * 32 + g * 8]);
    __builtin_amdgcn_s_setprio(1);
#pragma unroll
    for (int nf = 0; nf < 8; nf++) {
      int r = nf * 16 + l15;
#pragma unroll
      for (int kk = 0; kk < 2; kk++) {
        int ps = (kk * 4 + g) ^ (r & 7);
        bf16x8 b = *(const bf16x8*)(&KV[8192 + r * 64 + ps * 8]);
        oacc[nf] = __builtin_amdgcn_mfma_f32_16x16x32_bf16(pa[kk], b, oacc[nf], 0, 0, 0);
      }
    }
    __builtin_amdgcn_s_setprio(0);
    __builtin_amdgcn_s_barrier();   // all reads done before next stage
  }

  float lr[4];
#pragma unroll
  for (int r = 0; r < 4; r++) lr[r] = __shfl(lrow, g * 4 + r, 64);
#pragma unroll
  for (int nf = 0; nf < 8; nf++) {
#pragma unroll
    for (int r = 0; r < 4; r++) {
      int rowg = qb * 64 + w * 16 + g * 4 + r;
      float v = oacc[nf][r] / lr[r];
      O[(size_t)rowg * EMBED + h * HD + nf * 16 + l15] = f2bf(v);
    }
  }
}

extern "C" void kernel_launch(void* const* d_in, const int* in_sizes, int n_in,
                              void* d_out, int out_size, void* d_ws, size_t ws_size,
                              hipStream_t stream) {
  const float* x  = (const float*)d_in[0];
  const float* fc = (const float*)d_in[1];
  const float* wq = (const float*)d_in[2];
  const float* wk = (const float*)d_in[3];
  const float* wv = (const float*)d_in[4];
  const float* wo = (const float*)d_in[5];
  const int* sp = (const int*)d_in[6];

  char* ws = (char*)d_ws;
  u16* wqT = (u16*)(ws);                      // bf16 [4096][4096]
  u16* wkT = (u16*)(ws + 33554432ull);        // bf16 [2048][4096]
  u16* wvT = (u16*)(ws + 50331648ull);        // bf16 [2048][4096]
  u16* woT = (u16*)(ws + 67108864ull);        // bf16 [4096][4096]
  u16* xb  = (u16*)(ws + 100663296ull);       // bf16 [2048][4096]
  u16* Qb  = (u16*)(ws + 117440512ull);       // bf16 [2048][4096]
  u16* Kb  = (u16*)(ws + 134217728ull);       // bf16 [2048][2048]
  u16* Vt  = (u16*)(ws + 142606336ull);       // bf16 [2048][2048]
  u16* Ob  = (u16*)(ws + 150994944ull);       // bf16 [2048][4096]

  convert_x<<<dim3(2048), 256, 0, stream>>>(x, xb, SEQ * EMBED / 4);
  transpose_cvt<<<dim3(64, 64), 256, 0, stream>>>(wq, wqT, 4096, 4096);
  transpose_cvt<<<dim3(32, 64), 256, 0, stream>>>(wk, wkT, 4096, 2048);
  transpose_cvt<<<dim3(32, 64), 256, 0, stream>>>(wv, wvT, 4096, 2048);
  transpose_cvt<<<dim3(64, 64), 256, 0, stream>>>(wo, woT, 4096, 4096);

  gemm8_qkv<<<dim3(256), 512, 0, stream>>>(xb, wqT, wkT, wvT, Qb, Kb, Vt);
  rope_kernel<<<dim3(2048), 256, 0, stream>>>(Qb, Kb, fc, sp);
  attn_kernel<<<dim3(1024), 256, 0, stream>>>(Qb, Kb, Vt, Ob);
  gemm_bt_f32<<<dim3(16, 32), 256, 0, stream>>>(Ob, woT, (float*)d_out);
}

// Round 6
// 360.517 us; speedup vs baseline: 1.3515x; 1.0026x over previous
//
#include <hip/hip_runtime.h>
#include <stdint.h>

typedef unsigned short u16;
typedef __bf16 bf16x8 __attribute__((ext_vector_type(8)));
typedef float f32x4 __attribute__((ext_vector_type(4)));

#define SEQ   2048
#define EMBED 4096
#define KDIM  4096
#define NH    32
#define NKV   16
#define HD    128
#define KVW   2048   // N_KV_HEADS * HD

__device__ __forceinline__ float bf2f(u16 u) {
  union { uint32_t u; float f; } v; v.u = ((uint32_t)u) << 16; return v.f;
}
__device__ __forceinline__ u16 f2bf(float f) {
  union { float f; uint32_t u; } v; v.f = f;
  return (u16)((v.u + 0x7FFFu + ((v.u >> 16) & 1u)) >> 16);
}
__device__ __forceinline__ void g2l16(const u16* g, u16* l) {
  __builtin_amdgcn_global_load_lds(
      (const __attribute__((address_space(1))) uint32_t*)g,
      (__attribute__((address_space(3))) uint32_t*)l, 16, 0, 0);
}

// ---------------- x: f32 -> bf16, same layout ----------------
__global__ __launch_bounds__(256) void convert_x(
    const float* __restrict__ X, u16* __restrict__ Xb, int nquad) {
  for (int i = blockIdx.x * 256 + threadIdx.x; i < nquad;
       i += gridDim.x * 256) {
    float4 v = *(const float4*)(X + (size_t)i * 4);
    ushort4 o;
    o.x = f2bf(v.x); o.y = f2bf(v.y); o.z = f2bf(v.z); o.w = f2bf(v.w);
    *(ushort4*)(Xb + (size_t)i * 4) = o;
  }
}

// ---------------- transpose+convert: Wt[n][k] = bf16(W[k][n]) ----------------
__global__ __launch_bounds__(256) void transpose_cvt(
    const float* __restrict__ W, u16* __restrict__ Wt, int K, int N) {
  __shared__ u16 tile[64][68];
  const int t = threadIdx.x;
  const int n0 = blockIdx.x * 64, k0 = blockIdx.y * 64;
#pragma unroll
  for (int i = 0; i < 4; i++) {
    int c = i * 256 + t;
    int r = c >> 4, cq = c & 15;
    float4 v = *(const float4*)(W + (size_t)(k0 + r) * N + n0 + cq * 4);
    tile[r][cq * 4 + 0] = f2bf(v.x); tile[r][cq * 4 + 1] = f2bf(v.y);
    tile[r][cq * 4 + 2] = f2bf(v.z); tile[r][cq * 4 + 3] = f2bf(v.w);
  }
  __syncthreads();
#pragma unroll
  for (int i = 0; i < 4; i++) {
    int c = i * 256 + t;
    int rn = c >> 4, cq = c & 15;
    ushort4 v;
    v.x = tile[cq * 4 + 0][rn];
    v.y = tile[cq * 4 + 1][rn];
    v.z = tile[cq * 4 + 2][rn];
    v.w = tile[cq * 4 + 3][rn];
    *(ushort4*)(Wt + (size_t)(n0 + rn) * K + k0 + cq * 4) = v;
  }
}

// ================= 8-phase 256x256 GEMM for QKV =================
// Depth-2 prefetch for BOTH A and B: tile t+2 staged during iter t,
// single vmcnt(8) per K-tile (t+1 complete, t+2 in flight).
__global__ __launch_bounds__(512, 2) void gemm8_qkv(
    const u16* __restrict__ A,
    const u16* __restrict__ B0, const u16* __restrict__ B1,
    const u16* __restrict__ B2,
    u16* __restrict__ Qo, u16* __restrict__ Ko, u16* __restrict__ Vt) {
  __shared__ __align__(16) u16 As[2][256 * 64];
  __shared__ __align__(16) u16 Bs[2][256 * 64];
  const int t = threadIdx.x;
  const int lane = t & 63;
  const int w = t >> 6;
  const int wr = w >> 2;
  const int wc = w & 3;
  const int g = lane >> 4;
  const int l15 = lane & 15;

  const int bid = blockIdx.x;
  const int swz = (bid & 7) * 32 + (bid >> 3);
  const int mb = swz & 7;
  const int nb = swz >> 3;
  const int m0 = mb * 256;

  const u16* Bt; int nrow0;
  if (nb < 16)      { Bt = B0; nrow0 = nb * 256; }
  else if (nb < 24) { Bt = B1; nrow0 = (nb - 16) * 256; }
  else              { Bt = B2; nrow0 = (nb - 24) * 256; }

  auto stageA = [&](int buf, int kt, int h) {
#pragma unroll
    for (int i = 0; i < 2; i++) {
      int c = i * 512 + t;
      int row = c >> 3, sp = c & 7;
      int col = (sp ^ (row & 7)) << 3;
      g2l16(A + (size_t)(m0 + h * 128 + row) * KDIM + kt + col,
            &As[buf][h * 8192 + c * 8]);
    }
  };
  auto stageB = [&](int buf, int kt, int h) {
#pragma unroll
    for (int i = 0; i < 2; i++) {
      int c = i * 512 + t;
      int row = c >> 3, sp = c & 7;
      int col = (sp ^ (row & 7)) << 3;
      g2l16(Bt + (size_t)(nrow0 + h * 128 + row) * KDIM + kt + col,
            &Bs[buf][h * 8192 + c * 8]);
    }
  };

  f32x4 acc[8][4];
#pragma unroll
  for (int i = 0; i < 8; i++)
#pragma unroll
    for (int j = 0; j < 4; j++) acc[i][j] = (f32x4){0.f, 0.f, 0.f, 0.f};

  // prologue: tiles 0 and 1 fully staged (16 loads); wait tile 0 (8 left)
  stageA(0, 0, 0); stageA(0, 0, 1);
  stageB(0, 0, 0); stageB(0, 0, 1);
  stageA(1, 64, 0); stageA(1, 64, 1);
  stageB(1, 64, 0); stageB(1, 64, 1);
  asm volatile("s_waitcnt vmcnt(8)" ::: "memory");
  __builtin_amdgcn_s_barrier();

  const int NT = KDIM / 64;  // 64
  for (int ti = 0; ti < NT; ++ti) {
    const int cur = ti & 1;
    const u16* Asc = As[cur];
    const u16* Bsc = Bs[cur];
    const int ktn2 = (ti + 2) * 64;
    bf16x8 a0[2][4], a1[2][4], b0[2][2], b1[2][2];

    // ---- phase 0: read a0+b0 ; MFMA Q00 (acc[mi][ni] += a0*b0) ----
#pragma unroll
    for (int kk = 0; kk < 2; kk++)
#pragma unroll
      for (int mi = 0; mi < 4; mi++) {
        int r = wr * 128 + mi * 16 + l15;
        int slot = (kk * 4 + g) ^ (r & 7);
        a0[kk][mi] = *(const bf16x8*)(Asc + r * 64 + slot * 8);
      }
#pragma unroll
    for (int kk = 0; kk < 2; kk++)
#pragma unroll
      for (int ni = 0; ni < 2; ni++) {
        int r = wc * 64 + ni * 16 + l15;
        int slot = (kk * 4 + g) ^ (r & 7);
        b0[kk][ni] = *(const bf16x8*)(Bsc + r * 64 + slot * 8);
      }
    __builtin_amdgcn_s_barrier();
    asm volatile("s_waitcnt lgkmcnt(0)" ::: "memory");
    __builtin_amdgcn_sched_barrier(0);
    __builtin_amdgcn_s_setprio(1);
#pragma unroll
    for (int mi = 0; mi < 4; mi++)
#pragma unroll
      for (int ni = 0; ni < 2; ni++)
#pragma unroll
        for (int kk = 0; kk < 2; kk++)
          acc[mi][ni] = __builtin_amdgcn_mfma_f32_16x16x32_bf16(
              a0[kk][mi], b0[kk][ni], acc[mi][ni], 0, 0, 0);
    __builtin_amdgcn_s_setprio(0);
    __builtin_amdgcn_s_barrier();

    // ---- phase 1: read a1 ; MFMA Q10 (acc[mi+4][ni] += a1*b0) ----
#pragma unroll
    for (int kk = 0; kk < 2; kk++)
#pragma unroll
      for (int mi = 0; mi < 4; mi++) {
        int r = wr * 128 + 64 + mi * 16 + l15;
        int slot = (kk * 4 + g) ^ (r & 7);
        a1[kk][mi] = *(const bf16x8*)(Asc + r * 64 + slot * 8);
      }
    __builtin_amdgcn_s_barrier();
    asm volatile("s_waitcnt lgkmcnt(0)" ::: "memory");
    __builtin_amdgcn_sched_barrier(0);
    __builtin_amdgcn_s_setprio(1);
#pragma unroll
    for (int mi = 0; mi < 4; mi++)
#pragma unroll
      for (int ni = 0; ni < 2; ni++)
#pragma unroll
        for (int kk = 0; kk < 2; kk++)
          acc[mi + 4][ni] = __builtin_amdgcn_mfma_f32_16x16x32_bf16(
              a1[kk][mi], b0[kk][ni], acc[mi + 4][ni], 0, 0, 0);
    __builtin_amdgcn_s_setprio(0);
    __builtin_amdgcn_s_barrier();

    // ---- phase 2: read b1 ; stage A(t+2) ; MFMA Q11 (a1*b1) ----
    // (all A-reads of buf[cur] finished by end of phase 1 -> safe)
#pragma unroll
    for (int kk = 0; kk < 2; kk++)
#pragma unroll
      for (int ni = 0; ni < 2; ni++) {
        int r = wc * 64 + (ni + 2) * 16 + l15;
        int slot = (kk * 4 + g) ^ (r & 7);
        b1[kk][ni] = *(const bf16x8*)(Bsc + r * 64 + slot * 8);
      }
    if (ti + 2 < NT) { stageA(cur, ktn2, 0); stageA(cur, ktn2, 1); }
    __builtin_amdgcn_s_barrier();
    asm volatile("s_waitcnt lgkmcnt(0)" ::: "memory");
    __builtin_amdgcn_sched_barrier(0);
    __builtin_amdgcn_s_setprio(1);
#pragma unroll
    for (int mi = 0; mi < 4; mi++)
#pragma unroll
      for (int ni = 0; ni < 2; ni++)
#pragma unroll
        for (int kk = 0; kk < 2; kk++)
          acc[mi + 4][ni + 2] = __builtin_amdgcn_mfma_f32_16x16x32_bf16(
              a1[kk][mi], b1[kk][ni], acc[mi + 4][ni + 2], 0, 0, 0);
    __builtin_amdgcn_s_setprio(0);
    __builtin_amdgcn_s_barrier();

    // ---- phase 3: stage B(t+2) ; MFMA Q01 (a0*b1) ; vmcnt(8) ----
    // (all B-reads of buf[cur] finished by end of phase 2 -> safe)
    if (ti + 2 < NT) { stageB(cur, ktn2, 0); stageB(cur, ktn2, 1); }
    __builtin_amdgcn_s_barrier();
    __builtin_amdgcn_s_setprio(1);
#pragma unroll
    for (int mi = 0; mi < 4; mi++)
#pragma unroll
      for (int ni = 0; ni < 2; ni++)
#pragma unroll
        for (int kk = 0; kk < 2; kk++)
          acc[mi][ni + 2] = __builtin_amdgcn_mfma_f32_16x16x32_bf16(
              a0[kk][mi], b1[kk][ni], acc[mi][ni + 2], 0, 0, 0);
    __builtin_amdgcn_s_setprio(0);
    if (ti + 2 < NT)      asm volatile("s_waitcnt vmcnt(8)" ::: "memory");
    else if (ti + 1 < NT) asm volatile("s_waitcnt vmcnt(0)" ::: "memory");
    __builtin_amdgcn_s_barrier();
  }

#pragma unroll
  for (int mi = 0; mi < 8; mi++) {
#pragma unroll
    for (int ni = 0; ni < 4; ni++) {
      int rowg = m0 + wr * 128 + mi * 16 + g * 4;
      int ncol = nb * 256 + wc * 64 + ni * 16 + l15;
      if (nb < 16) {
#pragma unroll
        for (int r = 0; r < 4; r++)
          Qo[(size_t)(rowg + r) * EMBED + ncol] = f2bf(acc[mi][ni][r]);
      } else if (nb < 24) {
        int nc = ncol - 4096;
#pragma unroll
        for (int r = 0; r < 4; r++)
          Ko[(size_t)(rowg + r) * KVW + nc] = f2bf(acc[mi][ni][r]);
      } else {
        int nc = ncol - 6144;  // kv_head*128 + d
        ushort4 v;
        v.x = f2bf(acc[mi][ni][0]); v.y = f2bf(acc[mi][ni][1]);
        v.z = f2bf(acc[mi][ni][2]); v.w = f2bf(acc[mi][ni][3]);
        *(ushort4*)(Vt + (size_t)nc * SEQ + rowg) = v;
      }
    }
  }
}

// ================= out-proj: BM=128 x BN=256, 2-phase/K-tile, f32 out ======
// grid 256 (16 mb x 16 nb) -> full GPU. Depth-2 prefetch, vmcnt(6).
__global__ __launch_bounds__(512, 2) void gemm8_op(
    const u16* __restrict__ A, const u16* __restrict__ Bt,
    float* __restrict__ Cf) {
  __shared__ __align__(16) u16 As[2][128 * 64];
  __shared__ __align__(16) u16 Bs[2][256 * 64];
  const int t = threadIdx.x;
  const int lane = t & 63;
  const int w = t >> 6;
  const int wr = w >> 2;         // 0..1 -> M half (64 rows)
  const int wc = w & 3;          // 0..3 -> N quarter (64 cols)
  const int g = lane >> 4;
  const int l15 = lane & 15;

  const int bid = blockIdx.x;
  const int swz = (bid & 7) * 32 + (bid >> 3);
  const int mb = swz & 15;
  const int nb = swz >> 4;
  const int m0 = mb * 128;
  const int nrow0 = nb * 256;

  auto stageA = [&](int buf, int kt) {
#pragma unroll
    for (int i = 0; i < 2; i++) {
      int c = i * 512 + t;
      int row = c >> 3, sp = c & 7;
      int col = (sp ^ (row & 7)) << 3;
      g2l16(A + (size_t)(m0 + row) * KDIM + kt + col, &As[buf][c * 8]);
    }
  };
  auto stageB = [&](int buf, int kt) {
#pragma unroll
    for (int i = 0; i < 4; i++) {
      int c = i * 512 + t;
      int row = c >> 3, sp = c & 7;
      int col = (sp ^ (row & 7)) << 3;
      g2l16(Bt + (size_t)(nrow0 + row) * KDIM + kt + col, &Bs[buf][c * 8]);
    }
  };

  f32x4 acc[4][4];
#pragma unroll
  for (int i = 0; i < 4; i++)
#pragma unroll
    for (int j = 0; j < 4; j++) acc[i][j] = (f32x4){0.f, 0.f, 0.f, 0.f};

  stageA(0, 0); stageB(0, 0);
  stageA(1, 64); stageB(1, 64);
  asm volatile("s_waitcnt vmcnt(6)" ::: "memory");
  __builtin_amdgcn_s_barrier();

  const int NT = KDIM / 64;
  for (int ti = 0; ti < NT; ++ti) {
    const int cur = ti & 1;
    const u16* Asc = As[cur];
    const u16* Bsc = Bs[cur];
    const int ktn2 = (ti + 2) * 64;
    bf16x8 a[2][4], b0[2][2], b1[2][2];

    // ---- phase 0: read ALL (a, b0, b1 = 16 ds_reads) ; MFMA ni 0-1 ----
#pragma unroll
    for (int kk = 0; kk < 2; kk++)
#pragma unroll
      for (int mi = 0; mi < 4; mi++) {
        int r = wr * 64 + mi * 16 + l15;
        int slot = (kk * 4 + g) ^ (r & 7);
        a[kk][mi] = *(const bf16x8*)(Asc + r * 64 + slot * 8);
      }
#pragma unroll
    for (int kk = 0; kk < 2; kk++)
#pragma unroll
      for (int ni = 0; ni < 2; ni++) {
        int r = wc * 64 + ni * 16 + l15;
        int slot = (kk * 4 + g) ^ (r & 7);
        b0[kk][ni] = *(const bf16x8*)(Bsc + r * 64 + slot * 8);
      }
#pragma unroll
    for (int kk = 0; kk < 2; kk++)
#pragma unroll
      for (int ni = 0; ni < 2; ni++) {
        int r = wc * 64 + (ni + 2) * 16 + l15;
        int slot = (kk * 4 + g) ^ (r & 7);
        b1[kk][ni] = *(const bf16x8*)(Bsc + r * 64 + slot * 8);
      }
    __builtin_amdgcn_s_barrier();
    asm volatile("s_waitcnt lgkmcnt(0)" ::: "memory");
    __builtin_amdgcn_sched_barrier(0);
    __builtin_amdgcn_s_setprio(1);
#pragma unroll
    for (int mi = 0; mi < 4; mi++)
#pragma unroll
      for (int ni = 0; ni < 2; ni++)
#pragma unroll
        for (int kk = 0; kk < 2; kk++)
          acc[mi][ni] = __builtin_amdgcn_mfma_f32_16x16x32_bf16(
              a[kk][mi], b0[kk][ni], acc[mi][ni], 0, 0, 0);
    __builtin_amdgcn_s_setprio(0);
    __builtin_amdgcn_s_barrier();

    // ---- phase 1: stage tile t+2 (6 loads) ; MFMA ni 2-3 ; vmcnt(6) ----
    // (all ds_reads of buf[cur] happened in phase 0 -> staging safe)
    if (ti + 2 < NT) { stageA(cur, ktn2); stageB(cur, ktn2); }
    __builtin_amdgcn_s_barrier();
    __builtin_amdgcn_s_setprio(1);
#pragma unroll
    for (int mi = 0; mi < 4; mi++)
#pragma unroll
      for (int ni = 0; ni < 2; ni++)
#pragma unroll
        for (int kk = 0; kk < 2; kk++)
          acc[mi][ni + 2] = __builtin_amdgcn_mfma_f32_16x16x32_bf16(
              a[kk][mi], b1[kk][ni], acc[mi][ni + 2], 0, 0, 0);
    __builtin_amdgcn_s_setprio(0);
    if (ti + 2 < NT)      asm volatile("s_waitcnt vmcnt(6)" ::: "memory");
    else if (ti + 1 < NT) asm volatile("s_waitcnt vmcnt(0)" ::: "memory");
    __builtin_amdgcn_s_barrier();
  }

#pragma unroll
  for (int mi = 0; mi < 4; mi++)
#pragma unroll
    for (int ni = 0; ni < 4; ni++) {
      int rowg = m0 + wr * 64 + mi * 16 + g * 4;
      int ncol = nb * 256 + wc * 64 + ni * 16 + l15;
#pragma unroll
      for (int r = 0; r < 4; r++)
        Cf[(size_t)(rowg + r) * 4096 + ncol] = acc[mi][ni][r];
    }
}

// ---------------- RoPE (in place) on Q [2048][4096] and K [2048][2048] ----
__global__ __launch_bounds__(256) void rope_kernel(
    u16* __restrict__ Q, u16* __restrict__ Kb,
    const float* __restrict__ freqs, const int* __restrict__ start_pos) {
  const int sp = start_pos[0];
  const float qscale = 0.08838834764831845f;  // 1/sqrt(128)
  const int total_q = SEQ * EMBED / 2;
  const int total_k = SEQ * KVW / 2;
  const int total = total_q + total_k;
  for (int idx = blockIdx.x * 256 + threadIdx.x; idx < total;
       idx += gridDim.x * 256) {
    u16* buf; int row, pi; bool isq = idx < total_q;
    if (isq) { row = idx >> 11; pi = idx & 2047; buf = Q + (size_t)row * EMBED; }
    else { int j = idx - total_q; row = j >> 10; pi = j & 1023; buf = Kb + (size_t)row * KVW; }
    int i = pi & 63;
    float2 cs = *(const float2*)(freqs + (size_t)(sp + row) * 128 + i * 2);
    float c = cs.x, s = cs.y;
    ushort2 tv = *(ushort2*)(buf + pi * 2);
    float t0 = bf2f(tv.x), t1 = bf2f(tv.y);
    float o0 = t0 * c - t1 * s;
    float o1 = t0 * s + t1 * c;
    if (isq) { o0 *= qscale; o1 *= qscale; }
    ushort2 o; o.x = f2bf(o0); o.y = f2bf(o1);
    *(ushort2*)(buf + pi * 2) = o;
  }
}

// ---------------- flash attention, causal, GQA ----------------
// Swapped QK^T (mfma(K,Q)) -> lane owns one q-row: softmax is 2 shfl deep.
__global__ __launch_bounds__(256, 4) void attn_kernel(
    const u16* __restrict__ Q, const u16* __restrict__ Kb,
    const u16* __restrict__ Vt, u16* __restrict__ O) {
  __shared__ __align__(16) u16 KV[16384];   // K: [0,8192) 64x128, V: [8192,..) 128x64
  __shared__ u16 Ps[4][16 * 72];

  const int t = threadIdx.x;
  const int lane = t & 63;
  const int w = t >> 6;
  const int g = lane >> 4;
  const int l15 = lane & 15;
  const int bid = blockIdx.x;
  const int qb = 31 - (bid >> 5);
  const int h = bid & 31;
  const int hk = h >> 1;

  auto stageK = [&](int kv) {
#pragma unroll
    for (int i = 0; i < 4; i++) {
      int c = i * 256 + t;
      int row = c >> 4, spp = c & 15;
      int col = ((spp ^ (row & 7)) << 3);
      g2l16(Kb + (size_t)(kv * 64 + row) * KVW + hk * HD + col, &KV[c * 8]);
    }
  };
  auto stageV = [&](int kv) {
#pragma unroll
    for (int i = 0; i < 4; i++) {
      int c = i * 256 + t;
      int row = c >> 3, spp = c & 7;
      int col = ((spp ^ (row & 7)) << 3);
      g2l16(Vt + (size_t)(hk * HD + row) * SEQ + kv * 64 + col,
            &KV[8192 + c * 8]);
    }
  };

#pragma unroll
  for (int i = 0; i < 4; i++) {
    int c = i * 256 + t;
    int row = c >> 4, spp = c & 15;
    int col = ((spp ^ (row & 7)) << 3);
    g2l16(Q + (size_t)(qb * 64 + row) * EMBED + h * HD + col, &KV[c * 8]);
  }
  asm volatile("s_waitcnt vmcnt(0)" ::: "memory");
  __builtin_amdgcn_s_barrier();

  bf16x8 qf[4];
  {
    int r = w * 16 + l15;
#pragma unroll
    for (int kk = 0; kk < 4; kk++) {
      int ps = (kk * 4 + g) ^ (r & 7);
      qf[kk] = *(const bf16x8*)(&KV[r * 128 + ps * 8]);
    }
  }
  asm volatile("s_waitcnt lgkmcnt(0)" ::: "memory");
  __builtin_amdgcn_s_barrier();

  f32x4 oacc[8];
#pragma unroll
  for (int i = 0; i < 8; i++) oacc[i] = (f32x4){0.f, 0.f, 0.f, 0.f};
  float mrow = -1e30f, lrow = 0.f;
  const int qg = qb * 64 + w * 16 + l15;

  for (int kv = 0; kv <= qb; kv++) {
    stageK(kv); stageV(kv);
    asm volatile("s_waitcnt vmcnt(0)" ::: "memory");
    __builtin_amdgcn_s_barrier();

    f32x4 sfragT[4];
    __builtin_amdgcn_s_setprio(1);
#pragma unroll
    for (int ni = 0; ni < 4; ni++) {
      f32x4 s = (f32x4){0.f, 0.f, 0.f, 0.f};
      int r = ni * 16 + l15;
#pragma unroll
      for (int kk = 0; kk < 4; kk++) {
        int ps = (kk * 4 + g) ^ (r & 7);
        bf16x8 a = *(const bf16x8*)(&KV[r * 128 + ps * 8]);
        s = __builtin_amdgcn_mfma_f32_16x16x32_bf16(a, qf[kk], s, 0, 0, 0);
      }
      sfragT[ni] = s;
    }
    __builtin_amdgcn_s_setprio(0);

    if (kv == qb) {
#pragma unroll
      for (int ni = 0; ni < 4; ni++) {
        int colg = kv * 64 + ni * 16 + g * 4;
#pragma unroll
        for (int r = 0; r < 4; r++)
          if (colg + r > qg) sfragT[ni][r] = -1e30f;
      }
    }

    float m16 = sfragT[0][0];
#pragma unroll
    for (int ni = 0; ni < 4; ni++)
#pragma unroll
      for (int r = 0; r < 4; r++) m16 = fmaxf(m16, sfragT[ni][r]);
    m16 = fmaxf(m16, __shfl_xor(m16, 16));
    m16 = fmaxf(m16, __shfl_xor(m16, 32));
    float mnew = fmaxf(mrow, m16);
    float sc = __expf(mrow - mnew);
    mrow = mnew;

    float rsum = 0.f;
#pragma unroll
    for (int ni = 0; ni < 4; ni++) {
#pragma unroll
      for (int r = 0; r < 4; r++) {
        float p = __expf(sfragT[ni][r] - mrow);
        rsum += p;
        Ps[w][l15 * 72 + ni * 16 + g * 4 + r] = f2bf(p);
      }
    }
    rsum += __shfl_xor(rsum, 16);
    rsum += __shfl_xor(rsum, 32);
    lrow = lrow * sc + rsum;

    float scr[4];
#pragma unroll
    for (int r = 0; r < 4; r++) scr[r] = __shfl(sc, g * 4 + r, 64);
#pragma unroll
    for (int nf = 0; nf < 8; nf++)
#pragma unroll
      for (int r = 0; r < 4; r++) oacc[nf][r] *= scr[r];

    asm volatile("s_waitcnt lgkmcnt(0)" ::: "memory");

    bf16x8 pa[2];
#pragma unroll
    for (int kk = 0; kk < 2; kk++)
      pa[kk] = *(const bf16x8*)(&Ps[w][l15 * 72 + kk * 32 + g * 8]);
    __builtin_amdgcn_s_setprio(1);
#pragma unroll
    for (int nf = 0; nf < 8; nf++) {
      int r = nf * 16 + l15;
#pragma unroll
      for (int kk = 0; kk < 2; kk++) {
        int ps = (kk * 4 + g) ^ (r & 7);
        bf16x8 b = *(const bf16x8*)(&KV[8192 + r * 64 + ps * 8]);
        oacc[nf] = __builtin_amdgcn_mfma_f32_16x16x32_bf16(pa[kk], b, oacc[nf], 0, 0, 0);
      }
    }
    __builtin_amdgcn_s_setprio(0);
    __builtin_amdgcn_s_barrier();
  }

  float lr[4];
#pragma unroll
  for (int r = 0; r < 4; r++) lr[r] = __shfl(lrow, g * 4 + r, 64);
#pragma unroll
  for (int nf = 0; nf < 8; nf++) {
#pragma unroll
    for (int r = 0; r < 4; r++) {
      int rowg = qb * 64 + w * 16 + g * 4 + r;
      float v = oacc[nf][r] / lr[r];
      O[(size_t)rowg * EMBED + h * HD + nf * 16 + l15] = f2bf(v);
    }
  }
}

extern "C" void kernel_launch(void* const* d_in, const int* in_sizes, int n_in,
                              void* d_out, int out_size, void* d_ws, size_t ws_size,
                              hipStream_t stream) {
  const float* x  = (const float*)d_in[0];
  const float* fc = (const float*)d_in[1];
  const float* wq = (const float*)d_in[2];
  const float* wk = (const float*)d_in[3];
  const float* wv = (const float*)d_in[4];
  const float* wo = (const float*)d_in[5];
  const int* sp = (const int*)d_in[6];

  char* ws = (char*)d_ws;
  u16* wqT = (u16*)(ws);                      // bf16 [4096][4096]
  u16* wkT = (u16*)(ws + 33554432ull);        // bf16 [2048][4096]
  u16* wvT = (u16*)(ws + 50331648ull);        // bf16 [2048][4096]
  u16* woT = (u16*)(ws + 67108864ull);        // bf16 [4096][4096]
  u16* xb  = (u16*)(ws + 100663296ull);       // bf16 [2048][4096]
  u16* Qb  = (u16*)(ws + 117440512ull);       // bf16 [2048][4096]
  u16* Kb  = (u16*)(ws + 134217728ull);       // bf16 [2048][2048]
  u16* Vt  = (u16*)(ws + 142606336ull);       // bf16 [2048][2048]
  u16* Ob  = (u16*)(ws + 150994944ull);       // bf16 [2048][4096]

  convert_x<<<dim3(2048), 256, 0, stream>>>(x, xb, SEQ * EMBED / 4);
  transpose_cvt<<<dim3(64, 64), 256, 0, stream>>>(wq, wqT, 4096, 4096);
  transpose_cvt<<<dim3(32, 64), 256, 0, stream>>>(wk, wkT, 4096, 2048);
  transpose_cvt<<<dim3(32, 64), 256, 0, stream>>>(wv, wvT, 4096, 2048);
  transpose_cvt<<<dim3(64, 64), 256, 0, stream>>>(wo, woT, 4096, 4096);

  gemm8_qkv<<<dim3(256), 512, 0, stream>>>(xb, wqT, wkT, wvT, Qb, Kb, Vt);
  rope_kernel<<<dim3(2048), 256, 0, stream>>>(Qb, Kb, fc, sp);
  attn_kernel<<<dim3(1024), 256, 0, stream>>>(Qb, Kb, Vt, Ob);
  gemm8_op<<<dim3(256), 512, 0, stream>>>(Ob, woT, (float*)d_out);
}